// Round 1
// baseline (199.983 us; speedup 1.0000x reference)
//
#include <hip/hip_runtime.h>
#include <math.h>

#define DN 768            // embedding dim
#define NF4 (DN / 4)      // 192 float4 per row
#define NCLS 53           // n_class
#define BAGS_PER_BLOCK 8
#define BAGS_PER_WAVE 2   // 4 waves * 2

__global__ __launch_bounds__(256) void bag_attn_kernel(
    const float* __restrict__ x,      // [N, D]
    const int*   __restrict__ label,  // [N]
    const int*   __restrict__ seg,    // [N] sorted
    const float* __restrict__ w,      // [C, D]
    const float* __restrict__ bias,   // [C]
    float*       __restrict__ out,    // [B, C]
    int N, int Btot)
{
    __shared__ float s_repre[BAGS_PER_BLOCK][DN];   // 24 KB

    const int tid  = threadIdx.x;
    const int wave = tid >> 6;
    const int lane = tid & 63;
    const int bag_base = blockIdx.x * BAGS_PER_BLOCK;

    // ---------------- Phase 1: per-bag online-softmax pooling ----------------
    for (int sub = 0; sub < BAGS_PER_WAVE; ++sub) {
        const int slot = wave * BAGS_PER_WAVE + sub;
        const int b = bag_base + slot;
        if (b < Btot) {
            // lower_bound(seg, b) and lower_bound(seg, b+1) — uniform across lanes
            int lo = 0, hi = N;
            while (lo < hi) { int mid = (lo + hi) >> 1; if (seg[mid] < b) lo = mid + 1; else hi = mid; }
            const int start = lo;
            hi = N;
            while (lo < hi) { int mid = (lo + hi) >> 1; if (seg[mid] < b + 1) lo = mid + 1; else hi = mid; }
            const int end = lo;

            float m   = -INFINITY;
            float den = 0.f;
            float4 num0 = make_float4(0.f, 0.f, 0.f, 0.f);
            float4 num1 = make_float4(0.f, 0.f, 0.f, 0.f);
            float4 num2 = make_float4(0.f, 0.f, 0.f, 0.f);

            for (int j = start; j < end; ++j) {
                const float4* xr = (const float4*)(x + (size_t)j * DN);
                const float4* wr = (const float4*)(w + (size_t)label[j] * DN);
                float4 xv0 = xr[lane];        float4 wv0 = wr[lane];
                float4 xv1 = xr[lane + 64];   float4 wv1 = wr[lane + 64];
                float4 xv2 = xr[lane + 128];  float4 wv2 = wr[lane + 128];

                float dot = xv0.x*wv0.x + xv0.y*wv0.y + xv0.z*wv0.z + xv0.w*wv0.w
                          + xv1.x*wv1.x + xv1.y*wv1.y + xv1.z*wv1.z + xv1.w*wv1.w
                          + xv2.x*wv2.x + xv2.y*wv2.y + xv2.z*wv2.z + xv2.w*wv2.w;
                #pragma unroll
                for (int off = 1; off < 64; off <<= 1)
                    dot += __shfl_xor(dot, off, 64);

                // online softmax update (scale = exp(m - new_m); exp(-inf)=0 handles first row)
                const float new_m = fmaxf(m, dot);
                const float scale = __expf(m - new_m);
                const float e     = __expf(dot - new_m);
                den = den * scale + e;
                num0.x = num0.x*scale + e*xv0.x;  num0.y = num0.y*scale + e*xv0.y;
                num0.z = num0.z*scale + e*xv0.z;  num0.w = num0.w*scale + e*xv0.w;
                num1.x = num1.x*scale + e*xv1.x;  num1.y = num1.y*scale + e*xv1.y;
                num1.z = num1.z*scale + e*xv1.z;  num1.w = num1.w*scale + e*xv1.w;
                num2.x = num2.x*scale + e*xv2.x;  num2.y = num2.y*scale + e*xv2.y;
                num2.z = num2.z*scale + e*xv2.z;  num2.w = num2.w*scale + e*xv2.w;
                m = new_m;
            }

            // repre = num / max(den, nonzero); empty bag -> num==0 -> repre 0 either way
            const float inv = (den == 0.f) ? 0.f : 1.f / den;
            float4* sr = (float4*)s_repre[slot];
            float4 r0, r1, r2;
            r0.x = num0.x*inv; r0.y = num0.y*inv; r0.z = num0.z*inv; r0.w = num0.w*inv;
            r1.x = num1.x*inv; r1.y = num1.y*inv; r1.z = num1.z*inv; r1.w = num1.w*inv;
            r2.x = num2.x*inv; r2.y = num2.y*inv; r2.z = num2.z*inv; r2.w = num2.w*inv;
            sr[lane]       = r0;
            sr[lane + 64]  = r1;
            sr[lane + 128] = r2;
        }
    }
    __syncthreads();

    // ---------------- Phase 2: logits = repre @ w^T + bias ----------------
    for (int c = wave; c < NCLS; c += 4) {
        const float4* wr = (const float4*)(w + (size_t)c * DN);
        const float4 wv0 = wr[lane];
        const float4 wv1 = wr[lane + 64];
        const float4 wv2 = wr[lane + 128];
        const float bc = bias[c];

        #pragma unroll
        for (int g = 0; g < BAGS_PER_BLOCK; ++g) {
            if (bag_base + g >= Btot) break;
            const float4* sr = (const float4*)s_repre[g];
            const float4 r0 = sr[lane];
            const float4 r1 = sr[lane + 64];
            const float4 r2 = sr[lane + 128];
            float p = r0.x*wv0.x + r0.y*wv0.y + r0.z*wv0.z + r0.w*wv0.w
                    + r1.x*wv1.x + r1.y*wv1.y + r1.z*wv1.z + r1.w*wv1.w
                    + r2.x*wv2.x + r2.y*wv2.y + r2.z*wv2.z + r2.w*wv2.w;
            #pragma unroll
            for (int off = 1; off < 64; off <<= 1)
                p += __shfl_xor(p, off, 64);
            if (lane == 0)
                out[(size_t)(bag_base + g) * NCLS + c] = p + bc;
        }
    }
}

extern "C" void kernel_launch(void* const* d_in, const int* in_sizes, int n_in,
                              void* d_out, int out_size, void* d_ws, size_t ws_size,
                              hipStream_t stream)
{
    const float* x     = (const float*)d_in[0];
    const int*   label = (const int*)  d_in[1];
    const int*   seg   = (const int*)  d_in[2];
    const float* w     = (const float*)d_in[3];
    const float* bias  = (const float*)d_in[4];
    float*       out   = (float*)d_out;

    const int N = in_sizes[0] / DN;     // 131072
    const int B = out_size / NCLS;      // 16384

    const int blocks = (B + BAGS_PER_BLOCK - 1) / BAGS_PER_BLOCK;
    hipLaunchKernelGGL(bag_attn_kernel, dim3(blocks), dim3(256), 0, stream,
                       x, label, seg, w, bias, out, N, B);
}

// Round 2
// 189.979 us; speedup vs baseline: 1.0527x; 1.0527x over previous
//
#include <hip/hip_runtime.h>
#include <math.h>

#define DN 768            // embedding dim
#define NC 53             // n_class
#define GROUPS 16         // bags per block (16-lane group per bag)
#define RS 776            // padded LDS row stride in bf16 elems (768 + 8) -> bank-conflict-free

typedef __attribute__((ext_vector_type(8))) __bf16 bf16x8;
typedef __attribute__((ext_vector_type(8))) short short8v;
typedef __attribute__((ext_vector_type(4))) float f32x4;
typedef __attribute__((ext_vector_type(4))) unsigned short ushort4v;

// f32 -> bf16 bits, round-to-nearest-even (inputs are finite normals; no NaN path needed)
static __device__ __forceinline__ unsigned short f2bf(float f) {
    unsigned int u = __builtin_bit_cast(unsigned int, f);
    u = (u + 0x7FFFu + ((u >> 16) & 1u)) >> 16;
    return (unsigned short)u;
}

// offs[b] = lower_bound(seg, b) for b in [0, B]; seg is sorted. Boundary-scan, 1 thread/sentence.
__global__ void offs_kernel(const int* __restrict__ seg, int* __restrict__ offs,
                            int N, int B) {
    int i = blockIdx.x * blockDim.x + threadIdx.x;
    if (i >= N) return;
    int cur  = seg[i];
    int prev = (i == 0) ? -1 : seg[i - 1];
    for (int b = prev + 1; b <= cur; ++b) offs[b] = i;
    if (i == N - 1)
        for (int b = cur + 1; b <= B; ++b) offs[b] = N;
}

__global__ __launch_bounds__(256) void bag_attn_main(
    const float* __restrict__ x,      // [N, D]
    const int*   __restrict__ label,  // [N]
    const float* __restrict__ w,      // [C, D]
    const float* __restrict__ bias,   // [C]
    const int*   __restrict__ offs,   // [B+1]
    float*       __restrict__ out,    // [B, C]
    int Btot)
{
    __shared__ unsigned short s_rep[GROUPS * RS];   // repre in bf16 bits, 24832 B

    const int tid = threadIdx.x;
    const int grp = tid >> 4;          // 0..15 : bag slot in block
    const int l16 = tid & 15;          // lane within group
    const int bag = blockIdx.x * GROUPS + grp;

    // ---------------- Phase 1: online-softmax pooling, 16 lanes per bag ----------------
    float4 xv[12];
    float4 num[12];
    float m = -INFINITY, den = 0.f;
    #pragma unroll
    for (int i = 0; i < 12; ++i) num[i] = make_float4(0.f, 0.f, 0.f, 0.f);

    if (bag < Btot) {
        const int start = offs[bag];
        const int end   = offs[bag + 1];
        for (int j = start; j < end; ++j) {
            const float4* xr = (const float4*)(x + (size_t)j * DN);
            const float4* wr = (const float4*)(w + (size_t)label[j] * DN);
            #pragma unroll
            for (int i = 0; i < 12; ++i) xv[i] = xr[l16 + 16 * i];   // 16 lanes -> 256B contig per i
            float4 p = make_float4(0.f, 0.f, 0.f, 0.f);
            #pragma unroll
            for (int i = 0; i < 12; ++i) {
                const float4 wvv = wr[l16 + 16 * i];
                p.x += xv[i].x * wvv.x; p.y += xv[i].y * wvv.y;
                p.z += xv[i].z * wvv.z; p.w += xv[i].w * wvv.w;
            }
            float dot = (p.x + p.y) + (p.z + p.w);
            // 16-lane allreduce: masks < 16 stay inside the group; DPP-fast
            dot += __shfl_xor(dot, 1);
            dot += __shfl_xor(dot, 2);
            dot += __shfl_xor(dot, 4);
            dot += __shfl_xor(dot, 8);

            const float nm = fmaxf(m, dot);
            const float sc = __expf(m - nm);      // exp(-inf)=0 handles first row
            const float e  = __expf(dot - nm);
            den = den * sc + e;
            m = nm;
            #pragma unroll
            for (int i = 0; i < 12; ++i) {
                num[i].x = num[i].x * sc + e * xv[i].x;
                num[i].y = num[i].y * sc + e * xv[i].y;
                num[i].z = num[i].z * sc + e * xv[i].z;
                num[i].w = num[i].w * sc + e * xv[i].w;
            }
        }
    }
    const float inv = (den == 0.f) ? 0.f : 1.f / den;   // empty bag -> repre = 0
    #pragma unroll
    for (int i = 0; i < 12; ++i) {
        ushort4v h;
        h[0] = f2bf(num[i].x * inv);
        h[1] = f2bf(num[i].y * inv);
        h[2] = f2bf(num[i].z * inv);
        h[3] = f2bf(num[i].w * inv);
        *(ushort4v*)(&s_rep[grp * RS + (l16 + 16 * i) * 4]) = h;   // 8B aligned
    }
    __syncthreads();

    // ---------------- Phase 2: logits = repre @ W^T + bias via one MFMA col-tile per wave ----
    // mfma_f32_16x16x32_bf16; A = repre [16 bags x 768], B = W^T, wave wv4 -> classes wv4*16..+15
    const int lane = tid & 63;
    const int wv4  = tid >> 6;
    const int colc = wv4 * 16 + (lane & 15);           // class this lane's B-frag covers
    const int wrow = (colc < NC) ? colc : (NC - 1);    // clamp OOB class rows (outputs unused)
    const int kg   = (lane >> 4) * 8;                  // k sub-offset within each 32-wide step

    f32x4 acc = {0.f, 0.f, 0.f, 0.f};
    const unsigned short* arow = &s_rep[(lane & 15) * RS + kg];    // A: row = lane&15 (bag)
    const float* wbase = w + (size_t)wrow * DN + kg;
    #pragma unroll
    for (int ks = 0; ks < 24; ++ks) {
        const short8v a8 = *(const short8v*)(arow + ks * 32);      // 16B aligned (RS*2, kg*2, ks*64)
        const float* wp = wbase + ks * 32;
        const float4 b0 = *(const float4*)(wp);
        const float4 b1 = *(const float4*)(wp + 4);
        short8v b8;
        b8[0] = (short)f2bf(b0.x); b8[1] = (short)f2bf(b0.y);
        b8[2] = (short)f2bf(b0.z); b8[3] = (short)f2bf(b0.w);
        b8[4] = (short)f2bf(b1.x); b8[5] = (short)f2bf(b1.y);
        b8[6] = (short)f2bf(b1.z); b8[7] = (short)f2bf(b1.w);
        acc = __builtin_amdgcn_mfma_f32_16x16x32_bf16(
            __builtin_bit_cast(bf16x8, a8), __builtin_bit_cast(bf16x8, b8), acc, 0, 0, 0);
    }
    // C/D layout: col = lane&15 (class), row = (lane>>4)*4 + reg (bag)
    if (colc < NC) {
        const float bb = bias[colc];
        #pragma unroll
        for (int r = 0; r < 4; ++r) {
            const int row = (lane >> 4) * 4 + r;
            const int b = blockIdx.x * GROUPS + row;
            if (b < Btot) out[(size_t)b * NC + colc] = acc[r] + bb;
        }
    }
}

extern "C" void kernel_launch(void* const* d_in, const int* in_sizes, int n_in,
                              void* d_out, int out_size, void* d_ws, size_t ws_size,
                              hipStream_t stream)
{
    const float* x     = (const float*)d_in[0];
    const int*   label = (const int*)  d_in[1];
    const int*   seg   = (const int*)  d_in[2];
    const float* w     = (const float*)d_in[3];
    const float* bias  = (const float*)d_in[4];
    float*       out   = (float*)d_out;

    const int N = in_sizes[0] / DN;     // 131072
    const int B = out_size / NC;        // 16384

    int* offs = (int*)d_ws;             // (B+1) ints = 65.5 KB

    hipLaunchKernelGGL(offs_kernel, dim3((N + 255) / 256), dim3(256), 0, stream,
                       seg, offs, N, B);
    hipLaunchKernelGGL(bag_attn_main, dim3((B + GROUPS - 1) / GROUPS), dim3(256), 0, stream,
                       x, label, w, bias, offs, out, B);
}

// Round 3
// 166.041 us; speedup vs baseline: 1.2044x; 1.1442x over previous
//
#include <hip/hip_runtime.h>
#include <math.h>

#define DN  768
#define NC  53
#define NCP 64          // classes padded to 64 for MFMA tiles

typedef __attribute__((ext_vector_type(8))) __bf16 bf16x8;
typedef __attribute__((ext_vector_type(8))) short short8v;
typedef __attribute__((ext_vector_type(4))) float f32x4;

// f32 -> bf16 bits, round-to-nearest-even
static __device__ __forceinline__ unsigned short f2bf(float f) {
    unsigned int u = __builtin_bit_cast(unsigned int, f);
    u = (u + 0x7FFFu + ((u >> 16) & 1u)) >> 16;
    return (unsigned short)u;
}
static __device__ __forceinline__ float bf2f(unsigned short h) {
    unsigned int u = ((unsigned int)h) << 16;
    return __builtin_bit_cast(float, u);
}

// ---- k0: W -> Wh + Wl (bf16 split), zero-padded to 64 rows -----------------
__global__ void prep_w(const float* __restrict__ w,
                       unsigned short* __restrict__ wh,
                       unsigned short* __restrict__ wl) {
    int i = blockIdx.x * 256 + threadIdx.x;      // i = row*DN + col
    if (i >= NCP * DN) return;
    int row = i / DN;
    float v = (row < NC) ? w[i] : 0.f;
    unsigned short h = f2bf(v);
    wh[i] = h;
    wl[i] = f2bf(v - bf2f(h));
}

// ---- offs[b] = lower_bound(seg, b), b in [0, B] ----------------------------
__global__ void offs_kernel(const int* __restrict__ seg, int* __restrict__ offs,
                            int N, int B) {
    int i = blockIdx.x * blockDim.x + threadIdx.x;
    if (i >= N) return;
    int cur  = seg[i];
    int prev = (i == 0) ? -1 : seg[i - 1];
    for (int b = prev + 1; b <= cur; ++b) offs[b] = i;
    if (i == N - 1)
        for (int b = cur + 1; b <= B; ++b) offs[b] = N;
}

// ---- k1: Y[N][64] = bf16(X) @ (Wh+Wl)^T, f32 accum -------------------------
// block = 256 thr / 4 waves; wave M-tile = 64 rows (4 A-frags), full 64 cols.
__global__ __launch_bounds__(256) void gemm_y(
    const float* __restrict__ x,
    const unsigned short* __restrict__ wh,
    const unsigned short* __restrict__ wl,
    float* __restrict__ y) {
    const int lane = threadIdx.x & 63;
    const int wv   = threadIdx.x >> 6;
    const int r16  = lane & 15;
    const int kg   = (lane >> 4) * 8;            // k sub-offset within 32-wide step
    const long rowbase = ((long)blockIdx.x * 4 + wv) * 64;

    f32x4 acc[4][4];
    #pragma unroll
    for (int f = 0; f < 4; ++f)
        #pragma unroll
        for (int ct = 0; ct < 4; ++ct)
            acc[f][ct] = (f32x4){0.f, 0.f, 0.f, 0.f};

    const float* ap[4];
    #pragma unroll
    for (int f = 0; f < 4; ++f)
        ap[f] = x + (rowbase + f * 16 + r16) * DN + kg;
    const unsigned short* bph[4];
    const unsigned short* bpl[4];
    #pragma unroll
    for (int ct = 0; ct < 4; ++ct) {
        const int wr = ct * 16 + r16;
        bph[ct] = wh + wr * DN + kg;
        bpl[ct] = wl + wr * DN + kg;
    }

    #pragma unroll 2
    for (int ks = 0; ks < 24; ++ks) {
        const int kb = ks * 32;
        short8v a8[4];
        #pragma unroll
        for (int f = 0; f < 4; ++f) {
            const float4 u0 = *(const float4*)(ap[f] + kb);
            const float4 u1 = *(const float4*)(ap[f] + kb + 4);
            short8v t;
            t[0] = (short)f2bf(u0.x); t[1] = (short)f2bf(u0.y);
            t[2] = (short)f2bf(u0.z); t[3] = (short)f2bf(u0.w);
            t[4] = (short)f2bf(u1.x); t[5] = (short)f2bf(u1.y);
            t[6] = (short)f2bf(u1.z); t[7] = (short)f2bf(u1.w);
            a8[f] = t;
        }
        #pragma unroll
        for (int ct = 0; ct < 4; ++ct) {
            const short8v bh = *(const short8v*)(bph[ct] + kb);
            const short8v bl = *(const short8v*)(bpl[ct] + kb);
            #pragma unroll
            for (int f = 0; f < 4; ++f) {
                acc[f][ct] = __builtin_amdgcn_mfma_f32_16x16x32_bf16(
                    __builtin_bit_cast(bf16x8, a8[f]), __builtin_bit_cast(bf16x8, bh),
                    acc[f][ct], 0, 0, 0);
                acc[f][ct] = __builtin_amdgcn_mfma_f32_16x16x32_bf16(
                    __builtin_bit_cast(bf16x8, a8[f]), __builtin_bit_cast(bf16x8, bl),
                    acc[f][ct], 0, 0, 0);
            }
        }
    }

    // C/D layout: col = lane&15, row = (lane>>4)*4 + r
    #pragma unroll
    for (int f = 0; f < 4; ++f)
        #pragma unroll
        for (int ct = 0; ct < 4; ++ct) {
            const long row = rowbase + f * 16 + (lane >> 4) * 4;
            const int  col = ct * 16 + r16;
            #pragma unroll
            for (int r = 0; r < 4; ++r)
                y[(row + r) * NCP + col] = acc[f][ct][r];
        }
}

// ---- k2: per-bag softmax-weighted sum of Y rows + bias ---------------------
// one wave per bag; Y is L2/L3-resident (33.5 MB)
__global__ __launch_bounds__(256) void pool_kernel(
    const float* __restrict__ y,
    const int*   __restrict__ label,
    const int*   __restrict__ offs,
    const float* __restrict__ bias,
    float*       __restrict__ out,
    int Btot) {
    const int wv   = threadIdx.x >> 6;
    const int lane = threadIdx.x & 63;
    const int bag  = blockIdx.x * 4 + wv;
    if (bag >= Btot) return;
    const int s = offs[bag], e = offs[bag + 1];

    float m = -INFINITY, den = 0.f;
    for (int j = s; j < e; ++j) {
        const float a  = y[(long)j * NCP + label[j]];   // broadcast load
        const float nm = fmaxf(m, a);
        den = den * __expf(m - nm) + __expf(a - nm);
        m = nm;
    }
    float facc = 0.f;
    for (int j = s; j < e; ++j) {
        const float a = y[(long)j * NCP + label[j]];    // L1-hot
        const float c = __expf(a - m);
        facc += c * y[(long)j * NCP + lane];            // 256B coalesced
    }
    if (lane < NC) {
        const float inv = (den == 0.f) ? 0.f : 1.f / den;   // empty bag -> bias
        out[(long)bag * NC + lane] = facc * inv + bias[lane];
    }
}

extern "C" void kernel_launch(void* const* d_in, const int* in_sizes, int n_in,
                              void* d_out, int out_size, void* d_ws, size_t ws_size,
                              hipStream_t stream)
{
    const float* x     = (const float*)d_in[0];
    const int*   label = (const int*)  d_in[1];
    const int*   seg   = (const int*)  d_in[2];
    const float* w     = (const float*)d_in[3];
    const float* bias  = (const float*)d_in[4];
    float*       out   = (float*)d_out;

    const int N = in_sizes[0] / DN;     // 131072
    const int B = out_size / NC;        // 16384

    // ws layout
    unsigned short* wh   = (unsigned short*)d_ws;                       //  98304 B
    unsigned short* wl   = (unsigned short*)((char*)d_ws + 98304);      //  98304 B
    int*            offs = (int*)((char*)d_ws + 196608);                //  65540 B
    float*          y    = (float*)((char*)d_ws + 4194304);             //  33.5 MB

    hipLaunchKernelGGL(prep_w, dim3((NCP * DN + 255) / 256), dim3(256), 0, stream,
                       w, wh, wl);
    hipLaunchKernelGGL(offs_kernel, dim3((N + 255) / 256), dim3(256), 0, stream,
                       seg, offs, N, B);
    hipLaunchKernelGGL(gemm_y, dim3(N / 256), dim3(256), 0, stream,
                       x, wh, wl, y);
    hipLaunchKernelGGL(pool_kernel, dim3((B + 3) / 4), dim3(256), 0, stream,
                       y, label, offs, bias, out, B);
}